// Round 12
// baseline (213.741 us; speedup 1.0000x reference)
//
#include <hip/hip_runtime.h>
#include <math.h>

typedef _Float16 f16;
typedef unsigned short u16;
typedef unsigned int u32;
typedef f16 f16x8 __attribute__((ext_vector_type(8)));
typedef float f32x4 __attribute__((ext_vector_type(4)));

namespace {
constexpr int Kc  = 64;    // K
constexpr int SP1 = 5;     // S+1
constexpr int Mm  = 320;   // K*(S+1)
constexpr int DIM = 128;
constexpr int Nn  = 16;
constexpr int Pp  = 1200;
constexpr int PT  = 32;    // pixels per half-tile (one MFMA K-chunk for PV)
constexpr int NT  = 19;    // 64-px tiles (2 halves each)
constexpr int TPB = 512;   // 8 waves

// LDS layout (bytes), total 64768 -> 2 blocks/CU.
// conv region [OFF_CV..) is time-multiplexed per half:
//   x-scratch f32[32][132] (16896) -> conv f32[320][36] (46080) ->
//   softmax bufs: part[8][5][32] | m1f | z1f | ms f16[64][40] | xpv f16[128][40]
constexpr int OFF_BH   = 0;        // f16 [32][136] = 8704   (x^T hi, [p][c])
constexpr int OFF_BL   = 8704;     // f16 [32][136] = 8704
constexpr int OFF_CV   = 17408;    // f32 [320][36] = 46080
constexpr int OFF_PART = 17408;    // f32 [8][5][32] = 5120
constexpr int OFF_M1F  = 22528;    // f32 [5][32] = 640
constexpr int OFF_Z1F  = 23168;    // f32 [5][32] = 640
constexpr int OFF_MS   = 23808;    // f16 [64][40] = 5120
constexpr int OFF_XPV  = 28928;    // f16 [128][40] = 10240 (ends 39168 < 63488)
constexpr int OFF_BS   = 63488;    // f32 [320] = 1280
constexpr int LDS_TOTAL = 64768;
}

// ----------------------------------------------------------------- k_prep ---
// wave w of block b: centroid row m = b*16+w -> bias + f16 hi/lo split.
__global__ __launch_bounds__(1024) void k_prep(
    const float* __restrict__ cent, float* __restrict__ b,
    u16* __restrict__ Ah, u16* __restrict__ Al) {
  const int w = threadIdx.x >> 6, lane = threadIdx.x & 63;
  const int m = blockIdx.x * 16 + w;
  const float v0 = cent[(size_t)m * DIM + lane];
  const float v1 = cent[(size_t)m * DIM + 64 + lane];
  float s = v0 * v0 + v1 * v1;
  #pragma unroll
  for (int off = 32; off > 0; off >>= 1) s += __shfl_down(s, off, 64);
  if (lane == 0) b[m] = -100.0f * sqrtf(s);   // -ALPHA * ||c||
  const f16 h0 = (f16)v0, h1 = (f16)v1;
  Ah[(size_t)m * DIM + lane]      = __builtin_bit_cast(u16, h0);
  Ah[(size_t)m * DIM + 64 + lane] = __builtin_bit_cast(u16, h1);
  Al[(size_t)m * DIM + lane]      = __builtin_bit_cast(u16, (f16)(v0 - (float)h0));
  Al[(size_t)m * DIM + 64 + lane] = __builtin_bit_cast(u16, (f16)(v1 - (float)h1));
}

// --------------------------------------------------------------- k_fused ----
// 8 waves, 64-px tile as 2 halves of 32 px. A-fragments load straight from
// global (L2-hot, shared by all blocks) - no A staging, 64.8KB LDS, 2 blk/CU.
__global__ __launch_bounds__(TPB, 4) void k_fused(
    const float* __restrict__ x, const u16* __restrict__ Ah_g,
    const u16* __restrict__ Al_g, const float* __restrict__ b_g,
    float* __restrict__ out_part, float* __restrict__ S_part) {
  const int tile = blockIdx.x, n = blockIdx.y;
  const int t = threadIdx.x, lane = t & 63, w = t >> 6;
  const int l15 = lane & 15, g = lane >> 4;     // MFMA lane decomposition
  const int pp = t & 31, kgrp = t >> 5;         // softmax map (kgrp 0..15)

  __shared__ __align__(16) char smem[LDS_TOTAL];
  f16*   Bh      = (f16*)(smem + OFF_BH);
  u32*   Bh32    = (u32*)(smem + OFF_BH);
  u16*   BhU     = (u16*)(smem + OFF_BH);
  f16*   Bl      = (f16*)(smem + OFF_BL);
  u32*   Bl32    = (u32*)(smem + OFF_BL);
  float* convs   = (float*)(smem + OFF_CV);     // [320][36]
  float* scratch = (float*)(smem + OFF_CV);     // [32][132] (staging only)
  float* part    = (float*)(smem + OFF_PART);   // [8][5][32]
  float* m1f     = (float*)(smem + OFF_M1F);
  float* z1f     = (float*)(smem + OFF_Z1F);
  f16*   ms      = (f16*)(smem + OFF_MS);       // [64][40] ([k][p])
  f16*   xpv     = (f16*)(smem + OFF_XPV);      // [128][40] ([c][p])
  float* b_s     = (float*)(smem + OFF_BS);

  if (t < Mm) b_s[t] = b_g[t];                  // visible by first epilogue

  // conv wave map: wave covers m in [wm*80, wm*80+80), p-subtile wp
  const int wm = w >> 1, wp = w & 1;
  const int m0 = wm * 80;
  // PV wave map: k-tile (w&3), c-tiles (w>>2)*4 + 0..3
  const int ktile = w & 3, cbase = (w >> 2) * 4;

  f32x4 acc2[4];                                // PV acc, carried across halves
  #pragma unroll
  for (int i = 0; i < 4; ++i) acc2[i] = (f32x4){0.f, 0.f, 0.f, 0.f};
  float msum4[4] = {0.f, 0.f, 0.f, 0.f};

  for (int half = 0; half < 2; ++half) {
    const int p0 = tile * 64 + half * 32;
    const int cnt = min(PT, Pp - p0);

    __syncthreads();   // conv region (ms/xpv of prev half) free to reuse

    // ---- stage x f32 -> scratch [p][c] (coalesced in p) ----
    for (int i = t; i < PT * DIM; i += TPB) {   // 8 iters
      const int c = i >> 5, p = i & 31;
      scratch[p * 132 + c] = (p < cnt) ? x[((size_t)n * DIM + c) * Pp + p0 + p] : 0.f;
    }
    __syncthreads();
    // ---- f16 hi/lo split -> Bh, Bl [32][136] ----
    for (int i = t; i < PT * 64; i += TPB) {    // 4 iters
      const int p = i >> 6, c2 = i & 63;
      const float v0 = scratch[p * 132 + 2 * c2];
      const float v1 = scratch[p * 132 + 2 * c2 + 1];
      const f16 h0 = (f16)v0, h1 = (f16)v1;
      const f16 l0 = (f16)(v0 - (float)h0), l1 = (f16)(v1 - (float)h1);
      Bh32[p * 68 + c2] = (u32)__builtin_bit_cast(u16, h0) |
                          ((u32)__builtin_bit_cast(u16, h1) << 16);
      Bl32[p * 68 + c2] = (u32)__builtin_bit_cast(u16, l0) |
                          ((u32)__builtin_bit_cast(u16, l1) << 16);
    }
    __syncthreads();   // scratch dead; Bh/Bl ready

    // ---- conv MFMA: 3 segments, A-fragments from GLOBAL (L2-hot) ----
    f32x4 acc[5];
    #pragma unroll
    for (int i = 0; i < 5; ++i) acc[i] = (f32x4){0.f, 0.f, 0.f, 0.f};
    #pragma unroll
    for (int seg = 0; seg < 3; ++seg) {
      const u16* Aseg = (seg == 2) ? Al_g : Ah_g;
      const f16* Bseg = (seg == 1) ? Bl : Bh;
      #pragma unroll
      for (int kc = 0; kc < 4; ++kc) {
        const f16x8 bf = *(const f16x8*)&Bseg[(wp * 16 + l15) * 136 + kc * 32 + g * 8];
        #pragma unroll
        for (int t5 = 0; t5 < 5; ++t5) {
          const f16x8 af = *(const f16x8*)(Aseg +
              (size_t)(m0 + t5 * 16 + l15) * 128 + kc * 32 + g * 8);
          acc[t5] = __builtin_amdgcn_mfma_f32_16x16x32_f16(af, bf, acc[t5], 0, 0, 0);
        }
      }
    }
    // ---- epilogue: conv = 200*dot + b -> convs[m][p] (over dead scratch) ----
    const int pcol = wp * 16 + l15;
    #pragma unroll
    for (int t5 = 0; t5 < 5; ++t5)
      #pragma unroll
      for (int r = 0; r < 4; ++r) {
        const int m = m0 + t5 * 16 + g * 4 + r;  // C/D: row=(lane>>4)*4+reg, col=lane&15
        convs[m * 36 + pcol] = fmaf(200.0f, acc[t5][r], b_s[m]);
      }
    __syncthreads();

    // ---- softmax: thread = (kgrp, p); 4 k's each in registers ----
    float cv[4][SP1], m1loc[SP1];
    #pragma unroll
    for (int s = 0; s < SP1; ++s) m1loc[s] = -3.4e38f;
    #pragma unroll
    for (int kk = 0; kk < 4; ++kk) {
      const int k = kgrp * 4 + kk;
      #pragma unroll
      for (int s = 0; s < SP1; ++s) {
        const float v = convs[(k * SP1 + s) * 36 + pp];
        cv[kk][s] = v;
        m1loc[s] = fmaxf(m1loc[s], v);
      }
    }
    __syncthreads();   // conv region dead -> softmax bufs live

    // xpv[c][p] = (f16)x from Bh (no HBM re-read)
    for (int i = t; i < DIM * PT; i += TPB) {   // 8 iters
      const int c = i >> 5, p = i & 31;
      ((u16*)xpv)[c * 40 + p] = BhU[p * 136 + c];
    }

    // M1: fold intra-wave k-pair, then 8-wave LDS reduce
    #pragma unroll
    for (int s = 0; s < SP1; ++s)
      m1loc[s] = fmaxf(m1loc[s], __shfl_xor(m1loc[s], 32, 64));
    if (lane < 32) {
      #pragma unroll
      for (int s = 0; s < SP1; ++s) part[(w * SP1 + s) * 32 + pp] = m1loc[s];
    }
    __syncthreads();
    if (t < SP1 * 32) {
      const int s = t >> 5, l = t & 31;
      float m = part[s * 32 + l];
      #pragma unroll
      for (int ww = 1; ww < 8; ++ww) m = fmaxf(m, part[(ww * SP1 + s) * 32 + l]);
      m1f[s * 32 + l] = m;
    }
    __syncthreads();
    float m1r[SP1];
    #pragma unroll
    for (int s = 0; s < SP1; ++s) m1r[s] = m1f[s * 32 + pp];
    // Z1
    float z1loc[SP1] = {0.f, 0.f, 0.f, 0.f, 0.f};
    #pragma unroll
    for (int kk = 0; kk < 4; ++kk)
      #pragma unroll
      for (int s = 0; s < SP1; ++s) z1loc[s] += __expf(cv[kk][s] - m1r[s]);
    #pragma unroll
    for (int s = 0; s < SP1; ++s) z1loc[s] += __shfl_xor(z1loc[s], 32, 64);
    if (lane < 32) {
      #pragma unroll
      for (int s = 0; s < SP1; ++s) part[(w * SP1 + s) * 32 + pp] = z1loc[s];
    }
    __syncthreads();
    if (t < SP1 * 32) {
      const int s = t >> 5, l = t & 31;
      float z = part[s * 32 + l];
      #pragma unroll
      for (int ww = 1; ww < 8; ++ww) z += part[(ww * SP1 + s) * 32 + l];
      z1f[s * 32 + l] = z;
    }
    __syncthreads();
    float z1r[SP1];
    #pragma unroll
    for (int s = 0; s < SP1; ++s) z1r[s] = z1f[s * 32 + pp];

    // mult = prod_s(1 + sm1*sm2); write ms; accumulate per-k pixel sums
    const bool act = pp < cnt;
    #pragma unroll
    for (int kk = 0; kk < 4; ++kk) {
      const int k = kgrp * 4 + kk;
      float M2 = cv[kk][0];
      #pragma unroll
      for (int s = 1; s < SP1; ++s) M2 = fmaxf(M2, cv[kk][s]);
      float e2[SP1], Z2 = 0.f;
      #pragma unroll
      for (int s = 0; s < SP1; ++s) { e2[s] = __expf(cv[kk][s] - M2); Z2 += e2[s]; }
      float mlt = 1.f;
      #pragma unroll
      for (int s = 0; s < SP1; ++s) {
        const float e1 = __expf(cv[kk][s] - m1r[s]);
        mlt *= 1.f + (e1 / z1r[s]) * (e2[s] / Z2);
      }
      ms[k * 40 + pp] = act ? (f16)mlt : (f16)0.f;
      float msum = act ? mlt : 0.f;
      #pragma unroll
      for (int off = 16; off > 0; off >>= 1) msum += __shfl_down(msum, off, 32);
      msum4[kk] += msum;                         // lane pp==0 holds the sum
    }
    __syncthreads();   // ms + xpv complete

    // ---- PV MFMA (K=32 = this half's pixels), accumulate across halves ----
    const f16x8 am = *(const f16x8*)&ms[(ktile * 16 + l15) * 40 + g * 8];
    #pragma unroll
    for (int tn = 0; tn < 4; ++tn) {
      const f16x8 bx = *(const f16x8*)&xpv[((cbase + tn) * 16 + l15) * 40 + g * 8];
      acc2[tn] = __builtin_amdgcn_mfma_f32_16x16x32_f16(am, bx, acc2[tn], 0, 0, 0);
    }
  }

  // ---- store per-tile partials (deterministic, no atomics) ----
  float* dst = out_part + ((size_t)(n * NT + tile) * Kc) * DIM;
  #pragma unroll
  for (int tn = 0; tn < 4; ++tn)
    #pragma unroll
    for (int r = 0; r < 4; ++r)
      dst[(ktile * 16 + g * 4 + r) * DIM + (cbase + tn) * 16 + l15] = acc2[tn][r];
  if (pp == 0) {
    #pragma unroll
    for (int kk = 0; kk < 4; ++kk)
      S_part[((size_t)n * NT + tile) * Kc + kgrp * 4 + kk] = msum4[kk];
  }
}

// ---------------------------------------------------------------- k_norm ----
// (unchanged, verified) Reduce 19 partials, subtract rep*S, per-k normalize;
// global norm = 8 analytically.
__global__ __launch_bounds__(256) void k_norm(
    const float* __restrict__ out_part, const float* __restrict__ cent,
    const float* __restrict__ S_part, float* __restrict__ out) {
  const int n = blockIdx.y, k0 = blockIdx.x * 4;
  __shared__ float Sk[4];
  if (threadIdx.x < 4) {
    float s = 0.f;
    for (int tt = 0; tt < NT; ++tt)
      s += S_part[((size_t)n * NT + tt) * Kc + k0 + threadIdx.x];
    Sk[threadIdx.x] = s;
  }
  __syncthreads();
  const int kl = threadIdx.x >> 6, cl = threadIdx.x & 63;
  const int k = k0 + kl;
  const float sk = Sk[kl];
  float v[2], ss = 0.f;
  #pragma unroll
  for (int j = 0; j < 2; ++j) {
    const int c = cl + 64 * j;
    float a = 0.f;
    for (int tt = 0; tt < NT; ++tt)
      a += out_part[(((size_t)n * NT + tt) * Kc + k) * DIM + c];
    v[j] = a - cent[(size_t)k * SP1 * DIM + c] * sk;   // rep = centroids[:,0,:]
    ss = fmaf(v[j], v[j], ss);
  }
  #pragma unroll
  for (int off = 32; off > 0; off >>= 1) ss += __shfl_xor(ss, off, 64);
  const float kinv = 0.125f / fmaxf(sqrtf(ss), 1e-12f);
  #pragma unroll
  for (int j = 0; j < 2; ++j)
    out[((size_t)n * Kc + k) * DIM + cl + 64 * j] = v[j] * kinv;
}

// ----------------------------------------------------------------- launch ---
extern "C" void kernel_launch(void* const* d_in, const int* in_sizes, int n_in,
                              void* d_out, int out_size, void* d_ws, size_t ws_size,
                              hipStream_t stream) {
  const float* x    = (const float*)d_in[0];   // (16,128,30,40)
  const float* cent = (const float*)d_in[1];   // (64,5,128)
  float* out = (float*)d_out;

  // ws (floats): b[384] | S_part[16*19*64] | out_part[16*19*64*128]
  // then u16: Ah[40960] | Al[40960].  All fully written, no memset needed.
  float* b        = (float*)d_ws;
  float* S_part   = b + 384;
  float* out_part = S_part + (size_t)Nn * NT * Kc;
  u16* Ah_g = (u16*)(out_part + (size_t)Nn * NT * Kc * DIM);
  u16* Al_g = Ah_g + (size_t)Mm * DIM;

  k_prep<<<dim3(Mm / 16), dim3(1024), 0, stream>>>(cent, b, Ah_g, Al_g);
  k_fused<<<dim3(NT, Nn), dim3(TPB), 0, stream>>>(
      x, Ah_g, Al_g, b, out_part, S_part);
  k_norm<<<dim3(Kc / 4, Nn), dim3(256), 0, stream>>>(out_part, cent, S_part, out);
}